// Round 1
// 90.081 us; speedup vs baseline: 1.2225x; 1.2225x over previous
//
#include <hip/hip_runtime.h>

#define N 2048
#define ZD 64

typedef float f32x4 __attribute__((ext_vector_type(4)));
typedef float f32x2 __attribute__((ext_vector_type(2)));

// ws layout (f32): pT[128][N] transposed planes (P cols 0..63 with b1 folded,
// Q cols 64..127), then rp[32][N] rank-1 partials (p<16 sum to ri, p>=16 to rj).
// ri = P_i . W2, rj = Q_j . W2 for the relu split:
//   sum_k relu(P+Q)*w2 = 0.5*(ri + rj + sum_k |P+Q|*w2)

__global__ __launch_bounds__(256) void edge_proj(
    const float* __restrict__ z, const float* __restrict__ W1,
    const float* __restrict__ b1, const float* __restrict__ W2,
    float* __restrict__ pT)
{
    const int t = threadIdx.x;
    const int i = blockIdx.x * 64 + (t & 63);
    const int colg = t >> 6;                       // 0..3, wave-uniform
    const int col0 = blockIdx.y * 16 + colg * 4;   // blockIdx.y in 0..7

    float zr[ZD];
    const f32x4* zrow = (const f32x4*)(z + i * ZD);
    #pragma unroll
    for (int q = 0; q < ZD / 4; ++q) {
        f32x4 v = zrow[q];
        zr[q * 4 + 0] = v[0]; zr[q * 4 + 1] = v[1];
        zr[q * 4 + 2] = v[2]; zr[q * 4 + 3] = v[3];
    }

    float acc[4];
    #pragma unroll
    for (int cc = 0; cc < 4; ++cc) {
        const int col = __builtin_amdgcn_readfirstlane(col0 + cc);
        const float* w1c = (col < 64) ? (W1 + col) : (W1 + 64 * 64 + (col - 64));
        float a = (col < 64) ? b1[col] : 0.0f;
        #pragma unroll
        for (int d = 0; d < ZD; ++d)
            a = fmaf(zr[d], w1c[d * 64], a);
        acc[cc] = a;
        pT[(col0 + cc) * N + i] = a;   // coalesced: lanes = consecutive i
    }

    // exact f32 rank-1 partials (4 cols each -> 32 planes)
    float part = 0.0f;
    #pragma unroll
    for (int cc = 0; cc < 4; ++cc) {
        const int col = __builtin_amdgcn_readfirstlane(col0 + cc);
        part = fmaf(acc[cc], W2[col & 63], part);
    }
    float* rp = pT + 128 * N;
    const int p = blockIdx.y * 4 + colg;           // 0..31
    rp[p * N + i] = part;
}

// Block computes 64(i) x 128(j) tile. f32 abs-trick inner loop; adds expressed
// as float2 so the compiler may emit v_pk_add_f32 (exact same IEEE adds).
// Per 2 (out,k): 1 pk_add + 2 v_fma_f32(abs modifier) -> 1.5 VALU/(out*k).
__global__ __launch_bounds__(256) void edge_main2(
    const float* __restrict__ pT, const float* __restrict__ W2,
    const float* __restrict__ b2, float* __restrict__ out)
{
    __shared__ float ash[64][64];    // P tile: ash[k][i_local]
    __shared__ float bsh[64][128];   // Q tile: bsh[k][j_local]
    __shared__ float w2s[64];
    __shared__ float ris[64];
    __shared__ float rjs[128];

    const int t = threadIdx.x;
    const int i0 = blockIdx.y * 64;
    const int j0 = blockIdx.x * 128;
    const float* rp = pT + 128 * N;

    // Conflict-free staging: consecutive lanes -> consecutive LDS chunks.
    // (Old k=t>>2 layout had dword index k*64+f, bank = f&31 for all 16
    //  lanes of a q-group -> 16-way write conflict. Linear layout: zero.)
    {
        #pragma unroll
        for (int rep = 0; rep < 4; ++rep) {
            const int cidx = rep * 256 + t;          // f32x4 chunk id, linear
            const int k = cidx >> 4, c4 = (cidx & 15) << 2;
            *(f32x4*)&ash[k][c4] = *(const f32x4*)(pT + k * N + i0 + c4);
        }
        #pragma unroll
        for (int rep = 0; rep < 8; ++rep) {
            const int cidx = rep * 256 + t;
            const int k = cidx >> 5, c4 = (cidx & 31) << 2;
            *(f32x4*)&bsh[k][c4] = *(const f32x4*)(pT + (64 + k) * N + j0 + c4);
        }
        if (t < 64) {
            float s = 0.0f;
            #pragma unroll
            for (int p = 0; p < 16; ++p) s += rp[p * N + i0 + t];
            ris[t] = s;
        } else if (t < 192) {
            float s = 0.0f;
            #pragma unroll
            for (int p = 16; p < 32; ++p) s += rp[p * N + j0 + (t - 64)];
            rjs[t - 64] = s;
        } else {
            w2s[t - 192] = W2[t - 192];
        }
    }
    __syncthreads();

    const int tx = t & 15, ty = t >> 4;
    float acc[4][8];
    #pragma unroll
    for (int r = 0; r < 4; ++r)
        #pragma unroll
        for (int c = 0; c < 8; ++c) acc[r][c] = 0.0f;

    #pragma unroll 2
    for (int k4 = 0; k4 < 64; k4 += 4) {
        f32x4 wv = *(const f32x4*)&w2s[k4];
        #pragma unroll
        for (int kk = 0; kk < 4; ++kk) {
            const int k = k4 + kk;
            f32x4 av  = *(const f32x4*)&ash[k][ty * 4];        // 4 rows, bcast over tx
            f32x4 bv0 = *(const f32x4*)&bsh[k][tx * 4];        // 16 lanes x 16B contiguous
            f32x4 bv1 = *(const f32x4*)&bsh[k][64 + tx * 4];
            const float w = wv[kk];
            #pragma unroll
            for (int r = 0; r < 4; ++r) {
                f32x2 ar = { av[r], av[r] };                   // splat for pk_add
                #pragma unroll
                for (int c2 = 0; c2 < 2; ++c2) {
                    f32x2 b01 = { bv0[c2 * 2], bv0[c2 * 2 + 1] };
                    f32x2 t01 = ar + b01;                      // v_pk_add_f32 (exact)
                    acc[r][c2 * 2]     = fmaf(fabsf(t01[0]), w, acc[r][c2 * 2]);
                    acc[r][c2 * 2 + 1] = fmaf(fabsf(t01[1]), w, acc[r][c2 * 2 + 1]);
                    f32x2 b23 = { bv1[c2 * 2], bv1[c2 * 2 + 1] };
                    f32x2 t23 = ar + b23;
                    acc[r][c2 * 2 + 4] = fmaf(fabsf(t23[0]), w, acc[r][c2 * 2 + 4]);
                    acc[r][c2 * 2 + 5] = fmaf(fabsf(t23[1]), w, acc[r][c2 * 2 + 5]);
                }
            }
        }
    }

    // logit = 0.5*(ri + rj + abssum) + b2; x = -log2(e)*logit; y = 1/(1+2^x)
    const float C = -0.72134752f;                 // -log2(e)/2
    const float base = -1.44269504f * b2[0];
    float riC[4], rjC[8];
    #pragma unroll
    for (int r = 0; r < 4; ++r) riC[r] = fmaf(ris[ty * 4 + r], C, base);
    #pragma unroll
    for (int c = 0; c < 4; ++c) {
        rjC[c]     = rjs[tx * 4 + c] * C;
        rjC[c + 4] = rjs[64 + tx * 4 + c] * C;
    }

    #pragma unroll
    for (int r = 0; r < 4; ++r) {
        f32x4 o0, o1;
        #pragma unroll
        for (int c = 0; c < 4; ++c) {
            float x0 = fmaf(acc[r][c],     C, riC[r] + rjC[c]);
            float x1 = fmaf(acc[r][c + 4], C, riC[r] + rjC[c + 4]);
            o0[c] = __builtin_amdgcn_rcpf(1.0f + __builtin_amdgcn_exp2f(x0));
            o1[c] = __builtin_amdgcn_rcpf(1.0f + __builtin_amdgcn_exp2f(x1));
        }
        float* orow = out + (i0 + ty * 4 + r) * N + j0 + tx * 4;
        __builtin_nontemporal_store(o0, (f32x4*)orow);         // write-once output,
        __builtin_nontemporal_store(o1, (f32x4*)(orow + 64));  // keep L2 for pT
    }
}

extern "C" void kernel_launch(void* const* d_in, const int* in_sizes, int n_in,
                              void* d_out, int out_size, void* d_ws, size_t ws_size,
                              hipStream_t stream) {
    const float* z  = (const float*)d_in[0];
    const float* W1 = (const float*)d_in[1];
    const float* b1 = (const float*)d_in[2];
    const float* W2 = (const float*)d_in[3];
    const float* b2 = (const float*)d_in[4];
    float* out = (float*)d_out;
    float* pT  = (float*)d_ws;   // 128*N f32 planes + 32*N f32 rank-1 partials

    edge_proj<<<dim3(N / 64, 8), 256, 0, stream>>>(z, W1, b1, W2, pT);
    edge_main2<<<dim3(N / 128, N / 64), 256, 0, stream>>>(pT, W2, b2, out);
}